// Round 1
// baseline (239.470 us; speedup 1.0000x reference)
//
#include <hip/hip_runtime.h>
#include <math.h>

// Problem constants (from reference): w is [B, N] float32, L = 1.0
#define B_ROWS 16384
#define N_COLS 2048

// ---- ws layout (floats) ----
// [0*N, 1*N)  : colsum   (zeroed by memset, atomicAdd target)
// [1*N, 2*N)  : colsum2  (zeroed by memset, atomicAdd target)
// [2*N, 3*N)  : mean
// [3*N, 4*N)  : invstd
// [4*N, 4*N + K3_BLOCKS) : per-block partial sums of |pair_mean|
#define WS_COLSUM   0
#define WS_COLSUM2  (N_COLS)
#define WS_MEAN     (2 * N_COLS)
#define WS_INVSTD   (3 * N_COLS)
#define WS_PARTIALS (4 * N_COLS)

// ---------------- Pass 1: column sums (Sum w, Sum w^2) ----------------
// Each thread owns 4 consecutive columns (float4), iterates a row chunk.
// Grid = K1_COLGROUPS * K1_ROWCHUNKS blocks of 256 threads.
constexpr int K1_BLOCK = 256;
constexpr int K1_COLGROUPS = N_COLS / (K1_BLOCK * 4);     // = 2
constexpr int K1_ROWCHUNKS = 256;
constexpr int K1_ROWS_PER_CHUNK = B_ROWS / K1_ROWCHUNKS;  // = 64

__global__ __launch_bounds__(K1_BLOCK) void colstats_kernel(
    const float* __restrict__ w, float* __restrict__ ws) {
  const int cg = blockIdx.x % K1_COLGROUPS;
  const int rc = blockIdx.x / K1_COLGROUPS;
  const int col4 = cg * K1_BLOCK + threadIdx.x;  // float4 column index
  const int col = col4 * 4;
  const float4* __restrict__ w4 = reinterpret_cast<const float4*>(w);
  const int row_start = rc * K1_ROWS_PER_CHUNK;

  float sx = 0.f, sy = 0.f, sz = 0.f, sw = 0.f;
  float qx = 0.f, qy = 0.f, qz = 0.f, qw = 0.f;
#pragma unroll 4
  for (int r = 0; r < K1_ROWS_PER_CHUNK; ++r) {
    float4 v = w4[(size_t)(row_start + r) * (N_COLS / 4) + col4];
    sx += v.x; sy += v.y; sz += v.z; sw += v.w;
    qx = fmaf(v.x, v.x, qx);
    qy = fmaf(v.y, v.y, qy);
    qz = fmaf(v.z, v.z, qz);
    qw = fmaf(v.w, v.w, qw);
  }
  atomicAdd(&ws[WS_COLSUM + col + 0], sx);
  atomicAdd(&ws[WS_COLSUM + col + 1], sy);
  atomicAdd(&ws[WS_COLSUM + col + 2], sz);
  atomicAdd(&ws[WS_COLSUM + col + 3], sw);
  atomicAdd(&ws[WS_COLSUM2 + col + 0], qx);
  atomicAdd(&ws[WS_COLSUM2 + col + 1], qy);
  atomicAdd(&ws[WS_COLSUM2 + col + 2], qz);
  atomicAdd(&ws[WS_COLSUM2 + col + 3], qw);
}

// ---------------- Pass 1.5: mean / invstd ----------------
__global__ __launch_bounds__(256) void stats_finalize_kernel(float* __restrict__ ws) {
  const int n = blockIdx.x * 256 + threadIdx.x;
  if (n >= N_COLS) return;
  const float inv_b = 1.0f / (float)B_ROWS;
  float mean = ws[WS_COLSUM + n] * inv_b;
  float ex2 = ws[WS_COLSUM2 + n] * inv_b;
  float var = ex2 - mean * mean;
  ws[WS_MEAN + n] = mean;
  ws[WS_INVSTD + n] = 1.0f / sqrtf(var);
}

// ---------------- Pass 2: per-row s, s2 -> |pair_mean|, block partials ----------------
constexpr int K3_BLOCKS = 2048;
constexpr int ROWS_PER_BLOCK = B_ROWS / K3_BLOCKS;  // = 8 (2 rows per wave)

__global__ __launch_bounds__(256) void rowpass_kernel(
    const float* __restrict__ w, const float* __restrict__ ws,
    float* __restrict__ partials) {
  __shared__ float4 sm_mean[N_COLS / 4];   // 8 KiB
  __shared__ float4 sm_inv[N_COLS / 4];    // 8 KiB
  __shared__ float warpsum[4];

  const float4* __restrict__ g_mean = reinterpret_cast<const float4*>(ws + WS_MEAN);
  const float4* __restrict__ g_inv = reinterpret_cast<const float4*>(ws + WS_INVSTD);
  for (int i = threadIdx.x; i < N_COLS / 4; i += 256) {
    sm_mean[i] = g_mean[i];
    sm_inv[i] = g_inv[i];
  }
  __syncthreads();

  const int wid = threadIdx.x >> 6;
  const int lane = threadIdx.x & 63;
  constexpr float inv_pairs = 1.0f / ((float)N_COLS * (float)(N_COLS - 1));

  float acc = 0.f;
  for (int r = wid; r < ROWS_PER_BLOCK; r += 4) {
    const int row = blockIdx.x * ROWS_PER_BLOCK + r;
    const float4* __restrict__ row4 =
        reinterpret_cast<const float4*>(w + (size_t)row * N_COLS);
    float s = 0.f, s2 = 0.f;
#pragma unroll
    for (int k = 0; k < 8; ++k) {
      const int idx = lane + k * 64;
      float4 v = row4[idx];
      float4 m = sm_mean[idx];
      float4 iv = sm_inv[idx];
      float tx = (v.x - m.x) * iv.x;
      float ty = (v.y - m.y) * iv.y;
      float tz = (v.z - m.z) * iv.z;
      float tw = (v.w - m.w) * iv.w;
      s += (tx + ty) + (tz + tw);
      s2 += fmaf(tx, tx, fmaf(ty, ty, fmaf(tz, tz, tw * tw)));
    }
    // 64-lane butterfly reduce (all lanes end with the full sum)
#pragma unroll
    for (int off = 32; off > 0; off >>= 1) {
      s += __shfl_xor(s, off);
      s2 += __shfl_xor(s2, off);
    }
    float pm = (s * s - s2) * inv_pairs;
    acc += fabsf(pm);
  }

  if (lane == 0) warpsum[wid] = acc;
  __syncthreads();
  if (threadIdx.x == 0)
    partials[blockIdx.x] = (warpsum[0] + warpsum[1]) + (warpsum[2] + warpsum[3]);
}

// ---------------- Final reduce ----------------
__global__ __launch_bounds__(256) void final_reduce_kernel(
    const float* __restrict__ partials, float* __restrict__ out) {
  __shared__ float warpsum[4];
  float acc = 0.f;
  for (int i = threadIdx.x; i < K3_BLOCKS; i += 256) acc += partials[i];
#pragma unroll
  for (int off = 32; off > 0; off >>= 1) acc += __shfl_xor(acc, off);
  const int wid = threadIdx.x >> 6;
  const int lane = threadIdx.x & 63;
  if (lane == 0) warpsum[wid] = acc;
  __syncthreads();
  if (threadIdx.x == 0) {
    float total = (warpsum[0] + warpsum[1]) + (warpsum[2] + warpsum[3]);
    out[0] = total * (1.0f / (float)B_ROWS);  // L = 1.0
  }
}

extern "C" void kernel_launch(void* const* d_in, const int* in_sizes, int n_in,
                              void* d_out, int out_size, void* d_ws, size_t ws_size,
                              hipStream_t stream) {
  const float* w = reinterpret_cast<const float*>(d_in[0]);
  float* out = reinterpret_cast<float*>(d_out);
  float* ws = reinterpret_cast<float*>(d_ws);

  // Zero the atomic accumulator region (ws is poisoned 0xAA before each launch).
  hipMemsetAsync(ws, 0, 2 * N_COLS * sizeof(float), stream);

  colstats_kernel<<<K1_COLGROUPS * K1_ROWCHUNKS, K1_BLOCK, 0, stream>>>(w, ws);
  stats_finalize_kernel<<<(N_COLS + 255) / 256, 256, 0, stream>>>(ws);
  rowpass_kernel<<<K3_BLOCKS, 256, 0, stream>>>(w, ws, ws + WS_PARTIALS);
  final_reduce_kernel<<<1, 256, 0, stream>>>(ws + WS_PARTIALS, out);
}